// Round 1
// baseline (104.299 us; speedup 1.0000x reference)
//
#include <hip/hip_runtime.h>
#include <cmath>

// NSAB_5420248727612: per-row sigmoid-moment reductions + 2x2 Newton solve.
// B=2048 rows, N=8192 cols fp32. Memory-bound: 64 MiB read of x.
// One 256-thread block per row; float4 coalesced loads; 12 fp32 accumulators;
// wave shuffle reduce + LDS cross-wave; final scalar solve in double (den is
// a cancellation-prone subtraction; once per row so it's free).

#define THREADS 256

__device__ __forceinline__ float fast_exp2(float t) {
#if __has_builtin(__builtin_amdgcn_exp2f)
    return __builtin_amdgcn_exp2f(t);   // v_exp_f32
#else
    return exp2f(t);
#endif
}

__device__ __forceinline__ float fast_rcp(float t) {
#if __has_builtin(__builtin_amdgcn_rcpf)
    return __builtin_amdgcn_rcpf(t);    // v_rcp_f32 (~1 ulp)
#else
    return 1.0f / t;
#endif
}

__global__ __launch_bounds__(THREADS) void nsab_kernel(
    const float* __restrict__ x,
    const float* __restrict__ a,
    const float* __restrict__ b,
    const float* __restrict__ meanp,
    const float* __restrict__ varp,
    float* __restrict__ out,
    int B, int N)
{
    const int row = blockIdx.x;
    const int tid = threadIdx.x;

    const float av = a[row];
    const float bv = b[row];
    // s = 1/(1+exp(-(a*x+b))) = 1/(1+exp2(c1*x+c0)), c1=-a*log2(e), c0=-b*log2(e)
    const float LOG2E = 1.4426950408889634f;
    const float c1 = -av * LOG2E;
    const float c0 = -bv * LOG2E;

    const float4* __restrict__ xr = (const float4*)(x + (size_t)row * (size_t)N);
    const int nvec = N >> 2;

    // 12 row sums:
    //  0: s          -> fm
    //  1: s^2        -> m(f^2)
    //  2: sp         -> dem_db
    //  3: sp*x       -> dem_da
    //  4: spp        -> d2em_db2
    //  5: spp*x      -> d2em_dab
    //  6: spp*x^2    -> d2em_da2
    //  7: s*sp       -> m(f*df_db)
    //  8: s*sp*x     -> m(f*df_da)
    //  9: w          -> m(df_db^2 + f*d2f_db2)   where w = sp^2 + s*spp
    // 10: w*x        -> m(df_da*df_db + f*d2f_dab)
    // 11: w*x^2      -> m(df_da^2 + f*d2f_da2)
    float a_s = 0.f, a_ss = 0.f, a_sp = 0.f, a_spx = 0.f;
    float a_q = 0.f, a_qx = 0.f, a_qx2 = 0.f;
    float a_fsp = 0.f, a_fspx = 0.f;
    float a_w = 0.f, a_wx = 0.f, a_wx2 = 0.f;

    for (int i = tid; i < nvec; i += THREADS) {
        float4 v = xr[i];
        float xs[4] = {v.x, v.y, v.z, v.w};
        #pragma unroll
        for (int j = 0; j < 4; ++j) {
            const float xx = xs[j];
            const float e   = fast_exp2(fmaf(c1, xx, c0));   // exp(-(a x + b))
            const float s   = fast_rcp(1.0f + e);            // sigmoid
            const float sp  = s * (1.0f - s);                 // f'
            const float spp = sp * fmaf(-2.0f, s, 1.0f);      // f''
            const float ssp = s * sp;
            const float w   = fmaf(s, spp, sp * sp);          // sp^2 + s*spp
            const float x2  = xx * xx;

            a_s   += s;
            a_ss   = fmaf(s,   s,   a_ss);
            a_sp  += sp;
            a_spx  = fmaf(sp,  xx,  a_spx);
            a_q   += spp;
            a_qx   = fmaf(spp, xx,  a_qx);
            a_qx2  = fmaf(spp, x2,  a_qx2);
            a_fsp += ssp;
            a_fspx = fmaf(ssp, xx,  a_fspx);
            a_w   += w;
            a_wx   = fmaf(w,   xx,  a_wx);
            a_wx2  = fmaf(w,   x2,  a_wx2);
        }
    }

    float acc[12] = {a_s, a_ss, a_sp, a_spx, a_q, a_qx, a_qx2,
                     a_fsp, a_fspx, a_w, a_wx, a_wx2};

    // 64-lane wave butterfly reduce
    #pragma unroll
    for (int i = 0; i < 12; ++i) {
        float v = acc[i];
        #pragma unroll
        for (int off = 32; off > 0; off >>= 1)
            v += __shfl_down(v, off, 64);
        acc[i] = v;
    }

    __shared__ float part[THREADS / 64][12];
    const int wave = tid >> 6;
    const int lane = tid & 63;
    if (lane == 0) {
        #pragma unroll
        for (int i = 0; i < 12; ++i) part[wave][i] = acc[i];
    }
    __syncthreads();

    if (tid == 0) {
        double S[12];
        #pragma unroll
        for (int i = 0; i < 12; ++i)
            S[i] = (double)part[0][i] + (double)part[1][i]
                 + (double)part[2][i] + (double)part[3][i];

        const double invN = 1.0 / (double)N;
        const double fm       = S[0]  * invN;
        const double mff      = S[1]  * invN;
        const double dem_db   = S[2]  * invN;
        const double dem_da   = S[3]  * invN;
        const double d2em_db2 = S[4]  * invN;
        const double d2em_dab = S[5]  * invN;
        const double d2em_da2 = S[6]  * invN;
        const double m_fdfb   = S[7]  * invN;
        const double m_fdfa   = S[8]  * invN;
        const double m_w      = S[9]  * invN;
        const double m_wx     = S[10] * invN;
        const double m_wx2    = S[11] * invN;

        const double mv = (double)meanp[row];
        const double vv = (double)varp[row];

        const double em = fm - mv;
        const double ev = mff - fm * fm - vv;
        const double dev_da = 2.0 * (m_fdfa - fm * dem_da);
        const double dev_db = 2.0 * (m_fdfb - fm * dem_db);
        const double d2ev_da2 = 2.0 * (m_wx2 - dem_da * dem_da - fm * d2em_da2);
        const double d2ev_dab = 2.0 * (m_wx  - dem_da * dem_db - fm * d2em_dab);
        const double d2ev_db2 = 2.0 * (m_w   - dem_db * dem_db - fm * d2em_db2);

        const double dl_da = 2.0 * (em * dem_da + ev * dev_da);
        const double dl_db = 2.0 * (em * dem_db + ev * dev_db);
        const double d2l_da2 = 2.0 * (dem_da * dem_da + em * d2em_da2
                                    + dev_da * dev_da + ev * d2ev_da2);
        const double d2l_dab = 2.0 * (dem_da * dem_db + em * d2em_dab
                                    + dev_da * dev_db + ev * d2ev_dab);
        const double d2l_db2 = 2.0 * (dem_db * dem_db + em * d2em_db2
                                    + dev_db * dev_db + ev * d2ev_db2);

        const double den = d2l_da2 * d2l_db2 - d2l_dab * d2l_dab;
        const double na = (dl_da * d2l_db2 - dl_db * d2l_dab) / den;
        const double nb = (dl_db * d2l_da2 - dl_da * d2l_dab) / den;

        out[row]     = (float)na;
        out[B + row] = (float)nb;
    }
}

extern "C" void kernel_launch(void* const* d_in, const int* in_sizes, int n_in,
                              void* d_out, int out_size, void* d_ws, size_t ws_size,
                              hipStream_t stream) {
    const float* x    = (const float*)d_in[0];
    const float* a    = (const float*)d_in[1];
    const float* b    = (const float*)d_in[2];
    const float* mean = (const float*)d_in[3];
    const float* var  = (const float*)d_in[4];
    const int B = in_sizes[1];            // a is (B,1)
    const int N = in_sizes[0] / B;        // x is (B,N)
    float* out = (float*)d_out;

    nsab_kernel<<<dim3(B), dim3(THREADS), 0, stream>>>(x, a, b, mean, var, out, B, N);
}